// Round 1
// baseline (363.675 us; speedup 1.0000x reference)
//
#include <hip/hip_runtime.h>

#define B_SZ 4
#define SEQ 4096
#define DIN 1024
#define DH 1024
#define DOUT 1024
#define NBLK 8
#define MTOK (B_SZ * SEQ)      // 16384 tokens
#define CHUNK 64
#define NCHUNK (SEQ / CHUNK)   // 64

typedef _Float16 half8 __attribute__((ext_vector_type(8)));
typedef _Float16 half4v __attribute__((ext_vector_type(4)));
typedef float f32x4 __attribute__((ext_vector_type(4)));

// async global->LDS, 16B per lane. LDS dest must be wave-uniform; HW scatters
// to base + lane*16 (so LDS tiles are UNPADDED and laid out in lane order).
__device__ __forceinline__ void gl_lds16(const void* g, void* l) {
  __builtin_amdgcn_global_load_lds((__attribute__((address_space(1))) void*)g,
                                   (__attribute__((address_space(3))) void*)l,
                                   16, 0, 0);
}

// ---------------------------------------------------------------- converts
__global__ __launch_bounds__(256) void cvt_x_kernel(const float* __restrict__ src,
                                                    _Float16* __restrict__ dst) {
  const int gid = blockIdx.x * 256 + threadIdx.x;   // one float4 per thread
  const float4 v = ((const float4*)src)[gid];
  half4v h;
  h[0] = (_Float16)v.x; h[1] = (_Float16)v.y; h[2] = (_Float16)v.z; h[3] = (_Float16)v.w;
  ((half4v*)dst)[gid] = h;
}

__global__ void prep_c_kernel(const float* __restrict__ arp, float* __restrict__ cbuf) {
  const int d = blockIdx.x * 256 + threadIdx.x;
  if (d < DH) cbuf[d] = log1pf(expf(arp[d]));   // softplus(a_real_param)
}

// batched transpose + fp32->fp16:  src[z][R][C] -> dst[z][C][R]
__global__ __launch_bounds__(256) void transpose_cvt(const float* __restrict__ src,
                                                     _Float16* __restrict__ dst,
                                                     int R, int C) {
  __shared__ float tile[64][65];
  const size_t bo = (size_t)blockIdx.z * R * C;
  const int r0 = blockIdx.y * 64, c0 = blockIdx.x * 64;
  const int tr = threadIdx.x >> 6, tc = threadIdx.x & 63;
#pragma unroll
  for (int i = 0; i < 64; i += 4)
    tile[tr + i][tc] = src[bo + (size_t)(r0 + tr + i) * C + c0 + tc];
  __syncthreads();
#pragma unroll
  for (int i = 0; i < 64; i += 4) {
    const int cc = i + tr;
    dst[bo + (size_t)(c0 + cc) * R + r0 + tc] = (_Float16)tile[tc][cc];
  }
}

// ---------------------------------------------------------------- GEMM (m97 recipe)
// C[M,N] = A[M,K] * Bt[N,K]^T + bias ; 128x128 tile, 4 waves, BK=64, f16 MFMA.
template <int OUT_F32>
__global__ __launch_bounds__(256)
void gemm_bt(const _Float16* __restrict__ A, const _Float16* __restrict__ Bt,
             const float* __restrict__ bias, void* __restrict__ C,
             int M, int N, int K) {
  __shared__ __align__(16) _Float16 As[128 * 64];
  __shared__ __align__(16) _Float16 Bs[128 * 64];
  const int tid = threadIdx.x;
  const int wave = tid >> 6, lane = tid & 63;
  const int m0 = blockIdx.x * 128, n0 = blockIdx.y * 128;
  const int wm = (wave >> 1) * 64, wn = (wave & 1) * 64;
  const int row = lane & 15, quad = lane >> 4;
  const int srow = lane >> 3, scol = (lane & 7) * 8;   // staging: 8 rows x 64 elems / chunk

  f32x4 acc[4][4] = {};
  for (int kt = 0; kt < K; kt += 64) {
#pragma unroll
    for (int ci = 0; ci < 4; ci++) {
      const int c = wave * 4 + ci;
      gl_lds16(A  + (size_t)(m0 + c * 8 + srow) * K + kt + scol, As + c * 512);
      gl_lds16(Bt + (size_t)(n0 + c * 8 + srow) * K + kt + scol, Bs + c * 512);
    }
    __syncthreads();   // compiler drains vmcnt(0) before s_barrier
#pragma unroll
    for (int kk = 0; kk < 64; kk += 32) {
      half8 af[4], bf[4];
#pragma unroll
      for (int i = 0; i < 4; i++)
        af[i] = *(const half8*)&As[(wm + i * 16 + row) * 64 + kk + quad * 8];
#pragma unroll
      for (int i = 0; i < 4; i++)
        bf[i] = *(const half8*)&Bs[(wn + i * 16 + row) * 64 + kk + quad * 8];
#pragma unroll
      for (int i = 0; i < 4; i++)
#pragma unroll
        for (int j = 0; j < 4; j++)
          acc[i][j] = __builtin_amdgcn_mfma_f32_16x16x32_f16(af[i], bf[j], acc[i][j], 0, 0, 0);
    }
    __syncthreads();
  }
  // epilogue: C/D layout col=lane&15, row=quad*4+reg
#pragma unroll
  for (int j = 0; j < 4; j++) {
    const int n = n0 + wn + j * 16 + row;
    const float bv = bias[n];
#pragma unroll
    for (int i = 0; i < 4; i++) {
#pragma unroll
      for (int r = 0; r < 4; r++) {
        const int m = m0 + wm + i * 16 + quad * 4 + r;
        const float v = acc[i][j][r] + bv;
        if (OUT_F32) ((float*)C)[(size_t)m * N + n] = v;
        else         ((_Float16*)C)[(size_t)m * N + n] = (_Float16)v;
      }
    }
  }
}

// ---------------------------------------------------------------- gates
// One block = 128 tokens x one diag-block (BD=128). Both gate GEMMs off the
// shared X tile; epilogue computes a = exp(-8*sig(ga)*c), gx = sig(gx)*x*sqrt(1-a^2).
__global__ __launch_bounds__(256)
void gates_kernel(const _Float16* __restrict__ xp,
                  const _Float16* __restrict__ WxT, const _Float16* __restrict__ WaT,
                  const float* __restrict__ bgx, const float* __restrict__ bga,
                  const float* __restrict__ cbuf,
                  _Float16* __restrict__ a_out, _Float16* __restrict__ gx_out) {
  __shared__ __align__(16) _Float16 Xs[128 * 128];   // 32 KB
  __shared__ __align__(16) _Float16 Wx[128 * 64];    // 16 KB (K-half)
  __shared__ __align__(16) _Float16 Wa[128 * 64];    // 16 KB
  const int tid = threadIdx.x;
  const int wave = tid >> 6, lane = tid & 63;
  const int t0 = blockIdx.x * 128, nb = blockIdx.y;
  const int wm = (wave >> 1) * 64, wn = (wave & 1) * 64;
  const int row = lane & 15, quad = lane >> 4;

  // stage Xs: 32 chunks of 1KB (4 tokens x 128 ch each)
#pragma unroll
  for (int ci = 0; ci < 8; ci++) {
    const int c = wave * 8 + ci;
    const int tok = c * 4 + (lane >> 4);
    const int chb = (lane & 15) * 8;
    gl_lds16(xp + (size_t)(t0 + tok) * DH + nb * 128 + chb, Xs + c * 512);
  }
  const _Float16* WxB = WxT + (size_t)nb * 128 * 128;
  const _Float16* WaB = WaT + (size_t)nb * 128 * 128;
  f32x4 accx[4][4] = {}, acca[4][4] = {};
  for (int h = 0; h < 2; h++) {
    const int kb = h * 64;
#pragma unroll
    for (int ci = 0; ci < 4; ci++) {
      const int c = wave * 4 + ci;
      const int o = c * 8 + (lane >> 3);
      const int ii = (lane & 7) * 8;
      gl_lds16(WxB + (size_t)o * 128 + kb + ii, Wx + c * 512);
      gl_lds16(WaB + (size_t)o * 128 + kb + ii, Wa + c * 512);
    }
    __syncthreads();
#pragma unroll
    for (int kk = 0; kk < 64; kk += 32) {
      half8 af[4], bx[4], ba[4];
#pragma unroll
      for (int i = 0; i < 4; i++)
        af[i] = *(const half8*)&Xs[(wm + i * 16 + row) * 128 + kb + kk + quad * 8];
#pragma unroll
      for (int j = 0; j < 4; j++) {
        bx[j] = *(const half8*)&Wx[(wn + j * 16 + row) * 64 + kk + quad * 8];
        ba[j] = *(const half8*)&Wa[(wn + j * 16 + row) * 64 + kk + quad * 8];
      }
#pragma unroll
      for (int i = 0; i < 4; i++)
#pragma unroll
        for (int j = 0; j < 4; j++) {
          accx[i][j] = __builtin_amdgcn_mfma_f32_16x16x32_f16(af[i], bx[j], accx[i][j], 0, 0, 0);
          acca[i][j] = __builtin_amdgcn_mfma_f32_16x16x32_f16(af[i], ba[j], acca[i][j], 0, 0, 0);
        }
    }
    __syncthreads();
  }
  // epilogue (Xs still valid — never overwritten)
#pragma unroll
  for (int j = 0; j < 4; j++) {
    const int ch = wn + j * 16 + row;
    const int d = nb * 128 + ch;
    const float bxv = bgx[d], bav = bga[d], cd = cbuf[d];
#pragma unroll
    for (int i = 0; i < 4; i++) {
#pragma unroll
      for (int r = 0; r < 4; r++) {
        const int tl = wm + i * 16 + quad * 4 + r;
        const size_t gidx = (size_t)(t0 + tl) * DH + d;
        const float px = accx[i][j][r] + bxv;
        const float pa = acca[i][j][r] + bav;
        const float sx = 1.f / (1.f + __expf(-px));
        const float sa = 1.f / (1.f + __expf(-pa));
        const float log_a = -8.f * sa * cd;
        const float a = __expf(log_a);
        const float n2 = fmaxf(1.f - a * a, 0.f);
        const float xv = (float)Xs[tl * 128 + ch];
        a_out[gidx]  = (_Float16)a;
        gx_out[gidx] = (_Float16)(sx * xv * sqrtf(n2));
      }
    }
  }
}

// ---------------------------------------------------------------- 3-phase scan
// thread = (b, d, chunk c); lanes are consecutive d -> 128B coalesced per step
__global__ __launch_bounds__(256)
void scan_p1(const _Float16* __restrict__ a, const _Float16* __restrict__ gx,
             float* __restrict__ cA, float* __restrict__ cH) {
  const int gtid = blockIdx.x * 256 + threadIdx.x;
  const int d = gtid & (DH - 1);
  const int bc = gtid >> 10;
  const int b = bc >> 6, c = bc & (NCHUNK - 1);
  const size_t base = ((size_t)(b * SEQ + c * CHUNK)) * DH + d;
  float A = 1.f, h = 0.f;
#pragma unroll 4
  for (int i = 0; i < CHUNK; i++) {
    const float av = (float)a[base + (size_t)i * DH];
    const float gv = (float)gx[base + (size_t)i * DH];
    A *= av;
    h = fmaf(av, h, gv);
  }
  cA[c * (B_SZ * DH) + b * DH + d] = A;   // [c][b*DH+d] for coalesced P2/P3
  cH[c * (B_SZ * DH) + b * DH + d] = h;
}

__global__ void scan_p2(const float* __restrict__ cA, const float* __restrict__ cH,
                        const float* __restrict__ h0, float* __restrict__ cin,
                        float* __restrict__ hlast) {
  const int g = blockIdx.x * 256 + threadIdx.x;   // b*DH + d, 4096 total
  float carry = h0[g];
#pragma unroll 4
  for (int c = 0; c < NCHUNK; c++) {
    cin[c * (B_SZ * DH) + g] = carry;
    carry = fmaf(cA[c * (B_SZ * DH) + g], carry, cH[c * (B_SZ * DH) + g]);
  }
  hlast[g] = carry;   // == h[:, -1]
}

__global__ __launch_bounds__(256)
void scan_p3(const _Float16* __restrict__ a, const _Float16* __restrict__ gx,
             const float* __restrict__ cin, _Float16* __restrict__ h) {
  const int gtid = blockIdx.x * 256 + threadIdx.x;
  const int d = gtid & (DH - 1);
  const int bc = gtid >> 10;
  const int b = bc >> 6, c = bc & (NCHUNK - 1);
  const size_t base = ((size_t)(b * SEQ + c * CHUNK)) * DH + d;
  float carry = cin[c * (B_SZ * DH) + b * DH + d];
#pragma unroll 4
  for (int i = 0; i < CHUNK; i++) {
    const float av = (float)a[base + (size_t)i * DH];
    const float gv = (float)gx[base + (size_t)i * DH];
    carry = fmaf(av, carry, gv);
    h[base + (size_t)i * DH] = (_Float16)carry;
  }
}

// ---------------------------------------------------------------- launch
extern "C" void kernel_launch(void* const* d_in, const int* in_sizes, int n_in,
                              void* d_out, int out_size, void* d_ws, size_t ws_size,
                              hipStream_t stream) {
  const float* x     = (const float*)d_in[0];
  const float* h0    = (const float*)d_in[1];
  const float* W_in  = (const float*)d_in[2];
  const float* b_in  = (const float*)d_in[3];
  const float* Wgx   = (const float*)d_in[4];
  const float* bgx   = (const float*)d_in[5];
  const float* Wga   = (const float*)d_in[6];
  const float* bga   = (const float*)d_in[7];
  const float* arp   = (const float*)d_in[8];
  const float* W_out = (const float*)d_in[9];
  const float* b_out = (const float*)d_in[10];
  float* out = (float*)d_out;
  float* hlast = out + (size_t)MTOK * DOUT;

  char* p = (char*)d_ws;
  auto take = [&](size_t bytes) { char* r = p; p += (bytes + 255) & ~(size_t)255; return r; };
  _Float16* x_h   = (_Float16*)take((size_t)MTOK * DIN * 2);   // later reused as a_buf
  _Float16* xp    = (_Float16*)take((size_t)MTOK * DH * 2);    // later reused as h_buf
  _Float16* gxb   = (_Float16*)take((size_t)MTOK * DH * 2);
  _Float16* WinT  = (_Float16*)take((size_t)DIN * DH * 2);
  _Float16* WoutT = (_Float16*)take((size_t)DH * DOUT * 2);
  _Float16* WgxT  = (_Float16*)take((size_t)NBLK * 128 * 128 * 2);
  _Float16* WgaT  = (_Float16*)take((size_t)NBLK * 128 * 128 * 2);
  float* cbuf = (float*)take(DH * 4);
  float* cA   = (float*)take((size_t)NCHUNK * B_SZ * DH * 4);
  float* cH   = (float*)take((size_t)NCHUNK * B_SZ * DH * 4);
  float* cin  = (float*)take((size_t)NCHUNK * B_SZ * DH * 4);
  _Float16* a_buf = x_h;   // x_h dead after GEMM1
  _Float16* h_buf = xp;    // xp dead after gates

  cvt_x_kernel<<<MTOK * DIN / 1024, 256, 0, stream>>>(x, x_h);
  prep_c_kernel<<<(DH + 255) / 256, 256, 0, stream>>>(arp, cbuf);
  transpose_cvt<<<dim3(16, 16, 1), 256, 0, stream>>>(W_in, WinT, DIN, DH);
  transpose_cvt<<<dim3(2, 2, NBLK), 256, 0, stream>>>(Wgx, WgxT, 128, 128);
  transpose_cvt<<<dim3(2, 2, NBLK), 256, 0, stream>>>(Wga, WgaT, 128, 128);
  transpose_cvt<<<dim3(16, 16, 1), 256, 0, stream>>>(W_out, WoutT, DH, DOUT);

  gemm_bt<0><<<dim3(MTOK / 128, DH / 128), 256, 0, stream>>>(x_h, WinT, b_in, xp, MTOK, DH, DIN);
  gates_kernel<<<dim3(MTOK / 128, NBLK), 256, 0, stream>>>(xp, WgxT, WgaT, bgx, bga, cbuf, a_buf, gxb);
  scan_p1<<<(B_SZ * NCHUNK * DH) / 256, 256, 0, stream>>>(a_buf, gxb, cA, cH);
  scan_p2<<<(B_SZ * DH) / 256, 256, 0, stream>>>(cA, cH, h0, cin, hlast);
  scan_p3<<<(B_SZ * NCHUNK * DH) / 256, 256, 0, stream>>>(a_buf, gxb, cin, h_buf);
  gemm_bt<1><<<dim3(MTOK / 128, DOUT / 128), 256, 0, stream>>>(h_buf, WoutT, b_out, out, MTOK, DOUT, DH);
}